// Round 15
// baseline (301.782 us; speedup 1.0000x reference)
//
#include <hip/hip_runtime.h>
#include <stdint.h>

#define NTOK 196
#define KCL 49
#define IMG 224
#define IMG2 (224*224)
#define KB 64
#define NKT 12
#define LDP 68   // f32 cols + pad

typedef double f64x4 __attribute__((ext_vector_type(4)));

// ---------------- JAX threefry2x32 (20 rounds), host+device ----------------
__host__ __device__ __forceinline__ void tf2x32(uint32_t k0, uint32_t k1,
    uint32_t x0, uint32_t x1, uint32_t* o0, uint32_t* o1) {
  uint32_t ks2 = k0 ^ k1 ^ 0x1BD11BDAu;
#define TFR(r) { x0 += x1; x1 = (x1 << r) | (x1 >> (32 - r)); x1 ^= x0; }
  x0 += k0; x1 += k1;
  TFR(13) TFR(15) TFR(26) TFR(6)
  x0 += k1; x1 += ks2 + 1u;
  TFR(17) TFR(29) TFR(16) TFR(24)
  x0 += ks2; x1 += k0 + 2u;
  TFR(13) TFR(15) TFR(26) TFR(6)
  x0 += k0; x1 += k1 + 3u;
  TFR(17) TFR(29) TFR(16) TFR(24)
  x0 += k1; x1 += ks2 + 4u;
  TFR(13) TFR(15) TFR(26) TFR(6)
  x0 += ks2; x1 += k0 + 5u;
#undef TFR
  *o0 = x0; *o1 = x1;
}

// jax.random.uniform f32 bits, PARTITIONABLE threefry (jax >= 0.5 default)
__device__ __forceinline__ float jax_uniform(uint32_t k0, uint32_t k1, uint32_t j) {
  uint32_t o0, o1;
  tf2x32(k0, k1, 0u, j, &o0, &o1);
  uint32_t bits = o0 ^ o1;
  return __uint_as_float((bits >> 9) | 0x3f800000u) - 1.0f;
}

// ---------------- K1a: diagonal tiles — Gram + sq from diagonal (R12 form) --------
// grid: 8 xcd * 32 batch-groups * 7 diag-tiles = 1792 blocks of 256
__global__ void __launch_bounds__(256) k_diag(const float* __restrict__ x,
    double* __restrict__ sq, double* __restrict__ dist,
    unsigned long long* __restrict__ dmax) {
  int bid = blockIdx.x;
  int xcd = bid & 7;
  int s = bid >> 3;
  int b = xcd + 8 * (s / 7);
  int ti = s % 7;
  int n0b = ti * 32;
  int tid = threadIdx.x;

  __shared__ __align__(16) float As[32][LDP];
  __shared__ int rbN[32];
  __shared__ double prsh[3];
  __shared__ int okf;
  __shared__ double sqN[32];
  __shared__ double red2[256];

  if (tid < 32) {
    int n = n0b + tid; n = n < NTOK ? n : NTOK - 1;
    rbN[tid] = (n / 14) * 16 * IMG + (n % 14) * 16;
  }
  __syncthreads();

  const float* xb = x + (size_t)b * 3 * IMG2;
  int srow = tid >> 3;
  int sfo  = (tid & 7) * 8;
  int rN = rbN[srow];
  int lane = tid & 63;
  int wid  = tid >> 6;
  int wi = wid >> 1, wj = wid & 1;
  int aq = lane >> 4;
  const float* A0 = &As[0][0];
  int fragA = (wi * 16 + (lane & 15)) * LDP + aq;
  int fragB = (wj * 16 + (lane & 15)) * LDP + aq;

#define LOADD(d0,d1,kc) { int f0 = (kc) + sfo;                               \
    int c_ = f0 >> 8, h_ = (f0 >> 4) & 15, w_ = f0 & 15;                     \
    const float* p_ = xb + c_ * IMG2 + h_ * IMG + w_;                        \
    d0 = *(const float4*)(p_ + rN); d1 = *(const float4*)(p_ + rN + 4); }

  f64x4 acc = {0.0, 0.0, 0.0, 0.0};
  f64x4 acc0 = {0.0, 0.0, 0.0, 0.0};
  float4 ca0, ca1;
  LOADD(ca0, ca1, 0)

#pragma unroll
  for (int tt = 0; tt < NKT; ++tt) {
    __syncthreads();                // prev MFMA done reading LDS
    *(float4*)&As[srow][sfo]     = ca0;
    *(float4*)&As[srow][sfo + 4] = ca1;
    __syncthreads();                // staged
    float4 na0, na1;
    if (tt < NKT - 1) LOADD(na0, na1, (tt + 1) * KB)
#pragma unroll
    for (int k = 0; k < KB; k += 4) {
      double av = (double)A0[fragA + k];
      double bv = (double)A0[fragB + k];
      acc = __builtin_amdgcn_mfma_f64_16x16x4f64(av, bv, acc, 0, 0, 0);
    }
    if (tt == 0) {
      if (wid == 0) {               // layout probe on tile 0
        double q0 = (double)As[0][lane] * (double)As[0][lane];
        double q1 = (double)As[1][lane] * (double)As[0][lane];
        double q2 = (double)As[4][lane] * (double)As[0][lane];
#pragma unroll
        for (int off = 32; off; off >>= 1) {
          q0 += __shfl_down(q0, off);
          q1 += __shfl_down(q1, off);
          q2 += __shfl_down(q2, off);
        }
        if (lane == 0) { prsh[0] = q0; prsh[1] = q1; prsh[2] = q2; }
      }
      acc0 = acc;
    }
    ca0 = na0; ca1 = na1;
  }
#undef LOADD

  if (tid == 0) {
    double tol = 1e-9 * (1.0 + fabs(prsh[0]));
    int ok0  = fabs(prsh[0] - acc0[0]) <= tol;
    int okP1 = ok0 && (fabs(prsh[1] - acc0[1]) <= tol);
    int okP2 = ok0 && (fabs(prsh[2] - acc0[1]) <= tol);
    okf = okP1 ? 1 : (okP2 ? 2 : 0);
  }
  __syncthreads();
  int mode = okf;

  double (*Dt)[33] = (double(*)[33])A0;

  if (mode) {
#pragma unroll
    for (int i = 0; i < 4; ++i) {
      int lr = (mode == 1) ? (aq * 4 + i) : (aq + 4 * i);
      Dt[wi * 16 + lr][wj * 16 + (lane & 15)] = acc[i];
    }
  } else {
    // fallback: scalar f64 recompute
    double s00 = 0, s01 = 0, s10 = 0, s11 = 0;
    int ty2 = tid >> 4, tx2 = tid & 15;
    for (int kc = 0; kc < 768; kc += KB) {
      int f0 = kc + sfo;
      int c_ = f0 >> 8, h_ = (f0 >> 4) & 15, w_ = f0 & 15;
      const float* p_ = xb + c_ * IMG2 + h_ * IMG + w_;
      float4 la0 = *(const float4*)(p_ + rN), la1 = *(const float4*)(p_ + rN + 4);
      __syncthreads();
      *(float4*)&As[srow][sfo]     = la0;
      *(float4*)&As[srow][sfo + 4] = la1;
      __syncthreads();
      for (int j = 0; j < KB; ++j) {
        double a0 = (double)As[ty2][j], a1 = (double)As[ty2 + 16][j];
        double b0 = (double)As[tx2][j], b1 = (double)As[tx2 + 16][j];
        s00 += a0 * b0; s01 += a0 * b1; s10 += a1 * b0; s11 += a1 * b1;
      }
    }
    __syncthreads();
    Dt[ty2][tx2] = s00;       Dt[ty2][tx2 + 16] = s01;
    Dt[ty2 + 16][tx2] = s10;  Dt[ty2 + 16][tx2 + 16] = s11;
  }
  __syncthreads();

  // sq from Gram diagonal
  if (tid < 32) {
    double v = Dt[tid][tid];
    sqN[tid] = v;
    int n = n0b + tid;
    if (n < NTOK) sq[b * NTOK + n] = v;
  }
  __syncthreads();

  // Phase B: dist, per-batch max, coalesced write (no mirror)
  const double SQ768 = sqrt(768.0);
  int lr2 = tid >> 3, lc0 = (tid & 7) * 4;
  double dv[4];
  double lmax = 0.0;
#pragma unroll
  for (int j = 0; j < 4; ++j) {
    double d2 = sqN[lr2] + sqN[lc0 + j] - 2.0 * Dt[lr2][lc0 + j];
    double d = sqrt(d2 > 0.0 ? d2 : 0.0) / SQ768;
    dv[j] = d;
    lmax = lmax > d ? lmax : d;
  }
  red2[tid] = lmax;
  __syncthreads();
  for (int st = 128; st; st >>= 1) {
    if (tid < st) { double o = red2[tid + st]; if (o > red2[tid]) red2[tid] = o; }
    __syncthreads();
  }
  if (tid == 0) atomicMax(&dmax[b], (unsigned long long)__double_as_longlong(red2[0]));

  double* Db = dist + (size_t)b * NTOK * NTOK;
  int n = n0b + lr2, m0 = n0b + lc0;
  if (n < NTOK && m0 < NTOK) {
    if (m0 + 3 < NTOK) {
      f64x4 v = {dv[0], dv[1], dv[2], dv[3]};
      *(f64x4*)(Db + (size_t)n * NTOK + m0) = v;
    } else {
#pragma unroll
      for (int j = 0; j < 4; ++j)
        if (m0 + j < NTOK) Db[(size_t)n * NTOK + m0 + j] = dv[j];
    }
  }
}

// ---------------- K1b: off-diagonal tiles, K-split 2x2 per wave, mirror -----------
// grid: 8 xcd * 32 batch-groups * 21 offdiag-tiles = 5376 blocks of 256
// All 4 waves compute the SAME 32x32 tile, each over a 16-wide K-quarter;
// per k-step: 2 A-frags + 2 B-frags reused by 4 MFMAs (halves LDS-read issue).
__global__ void __launch_bounds__(256) k_offdiag(const float* __restrict__ x,
    const double* __restrict__ sq, double* __restrict__ dist,
    unsigned long long* __restrict__ dmax) {
  int bid = blockIdx.x;
  int xcd = bid & 7;
  int s = bid >> 3;
  int b = xcd + 8 * (s / 21);
  int t = s % 21;
  int ti = 0, rem = t, rl = 6;
  while (rem >= rl) { rem -= rl; rl--; ti++; }
  int tj = ti + 1 + rem;            // ti < tj
  int n0b = ti * 32, m0b = tj * 32;
  int tid = threadIdx.x;

  __shared__ __align__(16) float As[32][LDP];
  __shared__ __align__(16) float Bs[32][LDP];
  __shared__ int rbN[32], rbM[32];
  __shared__ int okf;

  if (tid < 32) {
    int n = n0b + tid; n = n < NTOK ? n : NTOK - 1;
    rbN[tid] = (n / 14) * 16 * IMG + (n % 14) * 16;
  } else if (tid < 64) {
    int m = m0b + (tid - 32); m = m < NTOK ? m : NTOK - 1;
    rbM[tid - 32] = (m / 14) * 16 * IMG + (m % 14) * 16;
  }
  __syncthreads();

  const float* xb = x + (size_t)b * 3 * IMG2;
  int srow = tid >> 3;
  int sfo  = (tid & 7) * 8;
  int rN = rbN[srow], rM = rbM[srow];
  int lane = tid & 63;
  int wid  = tid >> 6;
  int lr16 = lane & 15;
  int aq = lane >> 4;
  int kb0 = wid * 16;               // this wave's K-quarter base
  const float* Ap = &As[0][0];
  const float* Bp = &Bs[0][0];
  int fa0 = lr16 * LDP + kb0 + aq;
  int fa1 = (16 + lr16) * LDP + kb0 + aq;
  int fb0 = fa0;                    // same index pattern into Bs
  int fb1 = fa1;

#define LOADT(d0,d1,d2,d3,kc) { int f0 = (kc) + sfo;                         \
    int c_ = f0 >> 8, h_ = (f0 >> 4) & 15, w_ = f0 & 15;                     \
    const float* p_ = xb + c_ * IMG2 + h_ * IMG + w_;                        \
    d0 = *(const float4*)(p_ + rN); d1 = *(const float4*)(p_ + rN + 4);      \
    d2 = *(const float4*)(p_ + rM); d3 = *(const float4*)(p_ + rM + 4); }

  f64x4 acc00 = {0,0,0,0}, acc01 = {0,0,0,0}, acc10 = {0,0,0,0}, acc11 = {0,0,0,0};
  double q0 = 0.0, q1 = 0.0, q2 = 0.0;   // wave-0 full-K probe partials
  float4 ca0, ca1, cb0, cb1;
  LOADT(ca0, ca1, cb0, cb1, 0)

#pragma unroll
  for (int tt = 0; tt < NKT; ++tt) {
    __syncthreads();
    *(float4*)&As[srow][sfo]     = ca0;
    *(float4*)&As[srow][sfo + 4] = ca1;
    *(float4*)&Bs[srow][sfo]     = cb0;
    *(float4*)&Bs[srow][sfo + 4] = cb1;
    __syncthreads();
    float4 na0, na1, nb0, nb1;
    if (tt < NKT - 1) LOADT(na0, na1, nb0, nb1, (tt + 1) * KB)
#pragma unroll
    for (int ss = 0; ss < 4; ++ss) {
      int o = ss * 4;
      double a0 = (double)Ap[fa0 + o];
      double a1 = (double)Ap[fa1 + o];
      double b0 = (double)Bp[fb0 + o];
      double b1 = (double)Bp[fb1 + o];
      acc00 = __builtin_amdgcn_mfma_f64_16x16x4f64(a0, b0, acc00, 0, 0, 0);
      acc01 = __builtin_amdgcn_mfma_f64_16x16x4f64(a0, b1, acc01, 0, 0, 0);
      acc10 = __builtin_amdgcn_mfma_f64_16x16x4f64(a1, b0, acc10, 0, 0, 0);
      acc11 = __builtin_amdgcn_mfma_f64_16x16x4f64(a1, b1, acc11, 0, 0, 0);
    }
    if (wid == 0) {                 // probe accumulate (per-lane, full K)
      double bl = (double)Bs[0][lane];
      q0 += (double)As[0][lane] * bl;
      q1 += (double)As[1][lane] * bl;
      q2 += (double)As[4][lane] * bl;
    }
    ca0 = na0; ca1 = na1; cb0 = nb0; cb1 = nb1;
  }
#undef LOADT

  // ---- cross-wave reduction: waves 2,3 -> LDS; 0,1 add; 1 -> LDS; 0 adds ----
  double* R0 = (double*)&Bs[0][0];  // 8704 B >= 8192
  double* R1 = (double*)&As[0][0];
  __syncthreads();                  // all MFMA/probe reads of As/Bs done
#define STORE_ACC(R) {                                                        \
    R[(0*4+0)*64+lane]=acc00[0]; R[(0*4+1)*64+lane]=acc00[1];                 \
    R[(0*4+2)*64+lane]=acc00[2]; R[(0*4+3)*64+lane]=acc00[3];                 \
    R[(1*4+0)*64+lane]=acc01[0]; R[(1*4+1)*64+lane]=acc01[1];                 \
    R[(1*4+2)*64+lane]=acc01[2]; R[(1*4+3)*64+lane]=acc01[3];                 \
    R[(2*4+0)*64+lane]=acc10[0]; R[(2*4+1)*64+lane]=acc10[1];                 \
    R[(2*4+2)*64+lane]=acc10[2]; R[(2*4+3)*64+lane]=acc10[3];                 \
    R[(3*4+0)*64+lane]=acc11[0]; R[(3*4+1)*64+lane]=acc11[1];                 \
    R[(3*4+2)*64+lane]=acc11[2]; R[(3*4+3)*64+lane]=acc11[3]; }
#define ADD_ACC(R) {                                                          \
    acc00[0]+=R[(0*4+0)*64+lane]; acc00[1]+=R[(0*4+1)*64+lane];               \
    acc00[2]+=R[(0*4+2)*64+lane]; acc00[3]+=R[(0*4+3)*64+lane];               \
    acc01[0]+=R[(1*4+0)*64+lane]; acc01[1]+=R[(1*4+1)*64+lane];               \
    acc01[2]+=R[(1*4+2)*64+lane]; acc01[3]+=R[(1*4+3)*64+lane];               \
    acc10[0]+=R[(2*4+0)*64+lane]; acc10[1]+=R[(2*4+1)*64+lane];               \
    acc10[2]+=R[(2*4+2)*64+lane]; acc10[3]+=R[(2*4+3)*64+lane];               \
    acc11[0]+=R[(3*4+0)*64+lane]; acc11[1]+=R[(3*4+1)*64+lane];               \
    acc11[2]+=R[(3*4+2)*64+lane]; acc11[3]+=R[(3*4+3)*64+lane]; }
  if (wid == 2) STORE_ACC(R0)
  else if (wid == 3) STORE_ACC(R1)
  __syncthreads();
  if (wid == 0) ADD_ACC(R0)
  else if (wid == 1) ADD_ACC(R1)
  __syncthreads();
  if (wid == 1) STORE_ACC(R0)
  __syncthreads();
  if (wid == 0) ADD_ACC(R0)        // wave 0 now holds the full 32x32 tile
#undef STORE_ACC
#undef ADD_ACC

  // ---- probe finalize + mode select (wave 0) ----
  if (wid == 0) {
#pragma unroll
    for (int off = 32; off; off >>= 1) {
      q0 += __shfl_down(q0, off);
      q1 += __shfl_down(q1, off);
      q2 += __shfl_down(q2, off);
    }
    if (lane == 0) {
      // lane0 (aq=0,lr16=0) holds dot(0,0) in acc00[0]; dot(1,0) is acc00[1]
      // under mode1 (lr=aq*4+i), dot(4,0) is acc00[1] under mode2 (lr=aq+4i)
      double tol = 1e-9 * (1.0 + fabs(q0));
      int ok0  = fabs(q0 - acc00[0]) <= tol;
      int okP1 = ok0 && (fabs(q1 - acc00[1]) <= tol);
      int okP2 = ok0 && (fabs(q2 - acc00[1]) <= tol);
      okf = okP1 ? 1 : (okP2 ? 2 : 0);
    }
  }
  __syncthreads();
  int mode = okf;

  double (*Dt)[33] = (double(*)[33])(&As[0][0]);   // aliases R1 (consumed)

  if (mode) {
    if (wid == 0) {                 // wave 0 scatters the full tile
#pragma unroll
      for (int i = 0; i < 4; ++i) {
        int lr = (mode == 1) ? (aq * 4 + i) : (aq + 4 * i);
        Dt[lr][lr16]           = acc00[i];
        Dt[lr][16 + lr16]      = acc01[i];
        Dt[16 + lr][lr16]      = acc10[i];
        Dt[16 + lr][16 + lr16] = acc11[i];
      }
    }
  } else {
    // fallback: scalar f64 recompute from f32 LDS staging (R12-proven)
    double s00 = 0, s01 = 0, s10 = 0, s11 = 0;
    int ty2 = tid >> 4, tx2 = tid & 15;
    for (int kc = 0; kc < 768; kc += KB) {
      int f0 = kc + sfo;
      int c_ = f0 >> 8, h_ = (f0 >> 4) & 15, w_ = f0 & 15;
      const float* p_ = xb + c_ * IMG2 + h_ * IMG + w_;
      float4 la0 = *(const float4*)(p_ + rN), la1 = *(const float4*)(p_ + rN + 4);
      float4 lb0 = *(const float4*)(p_ + rM), lb1 = *(const float4*)(p_ + rM + 4);
      __syncthreads();
      *(float4*)&As[srow][sfo]     = la0;
      *(float4*)&As[srow][sfo + 4] = la1;
      *(float4*)&Bs[srow][sfo]     = lb0;
      *(float4*)&Bs[srow][sfo + 4] = lb1;
      __syncthreads();
      for (int j = 0; j < KB; ++j) {
        double a0 = (double)As[ty2][j], a1 = (double)As[ty2 + 16][j];
        double b0 = (double)Bs[tx2][j], b1 = (double)Bs[tx2 + 16][j];
        s00 += a0 * b0; s01 += a0 * b1; s10 += a1 * b0; s11 += a1 * b1;
      }
    }
    __syncthreads();
    Dt[ty2][tx2] = s00;       Dt[ty2][tx2 + 16] = s01;
    Dt[ty2 + 16][tx2] = s10;  Dt[ty2 + 16][tx2 + 16] = s11;
  }
  __syncthreads();

  // Phase B: dist, per-batch max, coalesced writes + mirror
  const double* sqb = sq + b * NTOK;
  const double SQ768 = sqrt(768.0);
  int lr2 = tid >> 3, lc0 = (tid & 7) * 4;
  double dv[4];
  double lmax = 0.0;
#pragma unroll
  for (int j = 0; j < 4; ++j) {
    int n = n0b + lr2, m = m0b + lc0 + j;
    int nn = n < NTOK ? n : NTOK - 1, mm = m < NTOK ? m : NTOK - 1;
    double d2 = sqb[nn] + sqb[mm] - 2.0 * Dt[lr2][lc0 + j];
    double d = sqrt(d2 > 0.0 ? d2 : 0.0) / SQ768;
    dv[j] = d;
    lmax = lmax > d ? lmax : d;
  }
#pragma unroll
  for (int j = 0; j < 4; ++j) Dt[lr2][lc0 + j] = dv[j];  // keep for mirror reads
  double* red = (double*)&Bs[0][0];
  red[tid] = lmax;
  __syncthreads();
  for (int st = 128; st; st >>= 1) {
    if (tid < st) { double o = red[tid + st]; if (o > red[tid]) red[tid] = o; }
    __syncthreads();
  }
  if (tid == 0) atomicMax(&dmax[b], (unsigned long long)__double_as_longlong(red[0]));

  double* Db = dist + (size_t)b * NTOK * NTOK;
  {
    int n = n0b + lr2, m0 = m0b + lc0;
    if (n < NTOK && m0 < NTOK) {
      if (m0 + 3 < NTOK) {
        f64x4 v = {dv[0], dv[1], dv[2], dv[3]};
        *(f64x4*)(Db + (size_t)n * NTOK + m0) = v;
      } else {
#pragma unroll
        for (int j = 0; j < 4; ++j)
          if (m0 + j < NTOK) Db[(size_t)n * NTOK + m0 + j] = dv[j];
      }
    }
  }
  {
    int m = m0b + lr2, n0 = n0b + lc0;
    if (m < NTOK && n0 < NTOK) {
      if (n0 + 3 < NTOK) {
        f64x4 v = {Dt[lc0][lr2], Dt[lc0 + 1][lr2], Dt[lc0 + 2][lr2], Dt[lc0 + 3][lr2]};
        *(f64x4*)(Db + (size_t)m * NTOK + n0) = v;
      } else {
#pragma unroll
        for (int j = 0; j < 4; ++j)
          if (n0 + j < NTOK) Db[(size_t)m * NTOK + n0 + j] = Dt[lc0 + j][lr2];
      }
    }
  }
}

// 5-NN insert (ascending 5-list in registers)
#define INS5(n0_,n1_,n2_,n3_,n4_,v_) {                                        \
  if ((v_) < n4_) { n4_ = (v_);                                               \
    if (n4_ < n3_) { double w_ = n3_; n3_ = n4_; n4_ = w_;                    \
      if (n3_ < n2_) { w_ = n2_; n2_ = n3_; n3_ = w_;                         \
        if (n2_ < n1_) { w_ = n1_; n1_ = n2_; n2_ = w_;                       \
          if (n1_ < n0_) { w_ = n0_; n0_ = n1_; n1_ = w_; } } } } } }

// merge two ascending 5-lists -> 5 smallest (ascending) into a[]
__device__ __forceinline__ void merge5(double a[5], const double b[5]) {
  double o[5];
  double ax = a[0], a1 = a[1], a2 = a[2], a3 = a[3], a4 = a[4];
  double bx = b[0], b1 = b[1], b2 = b[2], b3 = b[3], b4 = b[4];
#pragma unroll
  for (int p = 0; p < 5; ++p) {
    if (ax <= bx) { o[p] = ax; ax = a1; a1 = a2; a2 = a3; a3 = a4; a4 = 1e300; }
    else          { o[p] = bx; bx = b1; b1 = b2; b2 = b3; b3 = b4; b4 = 1e300; }
  }
#pragma unroll
  for (int p = 0; p < 5; ++p) a[p] = o[p];
}

// ---------------- K2: fused clustering, 1024 threads, 4-way m-scan split ----------
__global__ void __launch_bounds__(1024) k_cluster4(const double* __restrict__ dist,
    const unsigned long long* __restrict__ dmax, int* __restrict__ out,
    uint32_t kd0, uint32_t kd1, uint32_t kn0, uint32_t kn1, int B) {
  int b = blockIdx.x;
  int tid = threadIdx.x;
  int lane = tid & 63, wid = tid >> 6;
  int t = tid & 255, q = tid >> 8;
  bool act = t < NTOK;
  int m0 = q * 49;
  const double* Db = dist + (size_t)b * NTOK * NTOK;
  __shared__ double nbsh[2][NTOK][5];
  __shared__ double dens[NTOK];
  __shared__ double score[NTOK];
  __shared__ int center[KCL];
  __shared__ short center_of[NTOK];
  __shared__ unsigned long long bkey[KCL];
  double dmaxv = __longlong_as_double((long long)dmax[b]);

  // P1: partial 5-NN over quarter of the row (coalesced: Db[m][t]==dist[t][m])
  double nb[5] = {1e300, 1e300, 1e300, 1e300, 1e300};
  if (act) {
    const double* base = Db + t;
    for (int i = 0; i < 49; ++i) {
      double v = base[(size_t)(m0 + i) * NTOK];
      INS5(nb[0], nb[1], nb[2], nb[3], nb[4], v)
    }
    if (q == 1) {
#pragma unroll
      for (int p = 0; p < 5; ++p) nbsh[0][t][p] = nb[p];
    } else if (q == 3) {
#pragma unroll
      for (int p = 0; p < 5; ++p) nbsh[1][t][p] = nb[p];
    }
  }
  __syncthreads();
  if (act && q == 2) {             // merge q2+q3 -> nbsh[1]
    double ob[5];
#pragma unroll
    for (int p = 0; p < 5; ++p) ob[p] = nbsh[1][t][p];
    merge5(nb, ob);
#pragma unroll
    for (int p = 0; p < 5; ++p) nbsh[1][t][p] = nb[p];
  }
  __syncthreads();
  if (tid < NTOK) {                // q0: merge own+q1, then +(q2+q3)
    double ob[5];
#pragma unroll
    for (int p = 0; p < 5; ++p) ob[p] = nbsh[0][t][p];
    merge5(nb, ob);
#pragma unroll
    for (int p = 0; p < 5; ++p) ob[p] = nbsh[1][t][p];
    merge5(nb, ob);
    double acc = 0.0;
#pragma unroll
    for (int p = 0; p < 5; ++p) acc += nb[p] * nb[p];   // ascending sum
    double d = exp(-(acc / 5.0));
    double u = (double)jax_uniform(kd0, kd1, (uint32_t)(b * NTOK + t));
    dens[t] = d + u * 1e-6;
  }
  __syncthreads();

  // P2: dmin over strictly-higher-density tokens (filler = dist_max), 4-way split
  double vloc = dmaxv;
  if (act) {
    double dn = dens[t];
    const double* base = Db + t;
    for (int i = 0; i < 49; ++i) {
      double r = base[(size_t)(m0 + i) * NTOK];
      if (dens[m0 + i] > dn && r < vloc) vloc = r;
    }
  }
  __syncthreads();
  double* pm = &nbsh[0][0][0];
  if (act && q > 0) pm[(q - 1) * NTOK + t] = vloc;
  __syncthreads();
  if (tid < NTOK) {
    double v = vloc;
    double p1v = pm[t], p2v = pm[NTOK + t], p3v = pm[2 * NTOK + t];
    v = p1v < v ? p1v : v;
    v = p2v < v ? p2v : v;
    v = p3v < v ? p3v : v;
    score[t] = v * dens[t];
  }
  __syncthreads();

  // P3: iterative top-49 (ties -> lower index) on wave 0, scores in registers
  if (wid == 0) {
    double s0 = (lane < NTOK) ? score[lane] : -1e300;
    double s1 = score[lane + 64];
    double s2 = score[lane + 128];
    double s3 = (lane + 192 < NTOK) ? score[lane + 192] : -1e300;
    for (int k = 0; k < KCL; ++k) {
      double mv = s0; int mi = lane;
      if (s1 > mv) { mv = s1; mi = lane + 64; }
      if (s2 > mv) { mv = s2; mi = lane + 128; }
      if (s3 > mv) { mv = s3; mi = lane + 192; }
#pragma unroll
      for (int off = 32; off; off >>= 1) {
        double ov = __shfl_down(mv, off); int oi = __shfl_down(mi, off);
        if (ov > mv || (ov == mv && oi < mi)) { mv = ov; mi = oi; }
      }
      mi = __shfl(mi, 0);
      if (lane == 0) center[k] = mi;
      if (mi == lane) s0 = -1e300;
      else if (mi == lane + 64) s1 = -1e300;
      else if (mi == lane + 128) s2 = -1e300;
      else if (mi == lane + 192) s3 = -1e300;
    }
  }
  __syncthreads();

  // P4: assign to nearest center (ties -> lower k), centers self-assign
  if (tid < NTOK) center_of[tid] = -1;
  __syncthreads();
  if (tid < KCL) { center_of[center[tid]] = (short)tid; bkey[tid] = 0ULL; }
  __syncthreads();
  int mycl = 0;
  if (tid < NTOK) {
    double best = 1e300; int bk = 0;
    for (int k = 0; k < KCL; ++k) {
      double d = Db[(size_t)center[k] * NTOK + tid];
      if (d < best) { best = d; bk = k; }
    }
    short co = center_of[tid];
    if (co >= 0) bk = co;
    mycl = bk;
  }
  __syncthreads();

  // P5: representative = per-cluster max of f32 key (k+u), ties -> larger token index
  if (tid < NTOK) {
    float u = jax_uniform(kn0, kn1, (uint32_t)(b * NTOK + tid));
    float keyf = (float)mycl + u;
    unsigned long long key =
        ((unsigned long long)__float_as_uint(keyf) << 8) | (unsigned)tid;
    atomicMax(&bkey[mycl], key);
  }
  __syncthreads();
  if (tid < KCL) out[b * KCL + tid] = (int)(bkey[tid] & 0xFFu);
}

// ---------------- launch ----------------
extern "C" void kernel_launch(void* const* d_in, const int* in_sizes, int n_in,
                              void* d_out, int out_size, void* d_ws, size_t ws_size,
                              hipStream_t stream) {
  const float* x = (const float*)d_in[0];
  int B = in_sizes[0] / (3 * IMG2);           // 256
  double* dist = (double*)d_ws;
  size_t distBytes = (size_t)B * NTOK * NTOK * sizeof(double);
  double* sq = (double*)((char*)d_ws + distBytes);
  unsigned long long* dmax =
      (unsigned long long*)((char*)sq + (size_t)B * NTOK * sizeof(double));
  int* out = (int*)d_out;

  uint32_t kd0, kd1, kn0, kn1;
  tf2x32(0u, 1u, 0u, 0u, &kd0, &kd1);
  tf2x32(0u, 1u, 0u, 1u, &kn0, &kn1);

  hipMemsetAsync(dmax, 0, B * sizeof(unsigned long long), stream);
  k_diag<<<dim3(8 * 32 * 7), dim3(256), 0, stream>>>(x, sq, dist, dmax);
  k_offdiag<<<dim3(8 * 32 * 21), dim3(256), 0, stream>>>(x, sq, dist, dmax);
  k_cluster4<<<dim3(B), dim3(1024), 0, stream>>>(dist, dmax, out, kd0, kd1, kn0, kn1, B);
}

// Round 16
// 294.903 us; speedup vs baseline: 1.0233x; 1.0233x over previous
//
#include <hip/hip_runtime.h>
#include <stdint.h>

#define NTOK 196
#define KCL 49
#define IMG 224
#define IMG2 (224*224)
#define KB 64
#define NKT 12
#define LDP 68   // f32 cols + pad

typedef double f64x4 __attribute__((ext_vector_type(4)));

// ---------------- JAX threefry2x32 (20 rounds), host+device ----------------
__host__ __device__ __forceinline__ void tf2x32(uint32_t k0, uint32_t k1,
    uint32_t x0, uint32_t x1, uint32_t* o0, uint32_t* o1) {
  uint32_t ks2 = k0 ^ k1 ^ 0x1BD11BDAu;
#define TFR(r) { x0 += x1; x1 = (x1 << r) | (x1 >> (32 - r)); x1 ^= x0; }
  x0 += k0; x1 += k1;
  TFR(13) TFR(15) TFR(26) TFR(6)
  x0 += k1; x1 += ks2 + 1u;
  TFR(17) TFR(29) TFR(16) TFR(24)
  x0 += ks2; x1 += k0 + 2u;
  TFR(13) TFR(15) TFR(26) TFR(6)
  x0 += k0; x1 += k1 + 3u;
  TFR(17) TFR(29) TFR(16) TFR(24)
  x0 += k1; x1 += ks2 + 4u;
  TFR(13) TFR(15) TFR(26) TFR(6)
  x0 += ks2; x1 += k0 + 5u;
#undef TFR
  *o0 = x0; *o1 = x1;
}

// jax.random.uniform f32 bits, PARTITIONABLE threefry (jax >= 0.5 default)
__device__ __forceinline__ float jax_uniform(uint32_t k0, uint32_t k1, uint32_t j) {
  uint32_t o0, o1;
  tf2x32(k0, k1, 0u, j, &o0, &o1);
  uint32_t bits = o0 ^ o1;
  return __uint_as_float((bits >> 9) | 0x3f800000u) - 1.0f;
}

// ---------------- K1a: diagonal tiles — Gram + sq from diagonal -------------------
// grid: 8 xcd * 32 batch-groups * 7 diag-tiles = 1792 blocks of 256
__global__ void __launch_bounds__(256) k_diag(const float* __restrict__ x,
    double* __restrict__ sq, double* __restrict__ dist,
    unsigned long long* __restrict__ dmax) {
  int bid = blockIdx.x;
  int xcd = bid & 7;
  int s = bid >> 3;
  int b = xcd + 8 * (s / 7);
  int ti = s % 7;
  int n0b = ti * 32;
  int tid = threadIdx.x;

  __shared__ __align__(16) float As[32][LDP];
  __shared__ int rbN[32];
  __shared__ double prsh[3];
  __shared__ int okf;
  __shared__ double sqN[32];
  __shared__ double red2[256];

  if (tid < 32) {
    int n = n0b + tid; n = n < NTOK ? n : NTOK - 1;
    rbN[tid] = (n / 14) * 16 * IMG + (n % 14) * 16;
  }
  __syncthreads();

  const float* xb = x + (size_t)b * 3 * IMG2;
  int srow = tid >> 3;
  int sfo  = (tid & 7) * 8;
  int rN = rbN[srow];
  int lane = tid & 63;
  int wid  = tid >> 6;
  int wi = wid >> 1, wj = wid & 1;
  int aq = lane >> 4;
  const float* A0 = &As[0][0];
  int fragA = (wi * 16 + (lane & 15)) * LDP + aq;
  int fragB = (wj * 16 + (lane & 15)) * LDP + aq;

#define LOADD(d0,d1,kc) { int f0 = (kc) + sfo;                               \
    int c_ = f0 >> 8, h_ = (f0 >> 4) & 15, w_ = f0 & 15;                     \
    const float* p_ = xb + c_ * IMG2 + h_ * IMG + w_;                        \
    d0 = *(const float4*)(p_ + rN); d1 = *(const float4*)(p_ + rN + 4); }

  f64x4 acc = {0.0, 0.0, 0.0, 0.0};
  f64x4 acc0 = {0.0, 0.0, 0.0, 0.0};
  float4 ca0, ca1;
  LOADD(ca0, ca1, 0)

#pragma unroll
  for (int tt = 0; tt < NKT; ++tt) {
    __syncthreads();                // prev MFMA done reading LDS
    *(float4*)&As[srow][sfo]     = ca0;
    *(float4*)&As[srow][sfo + 4] = ca1;
    __syncthreads();                // staged
    float4 na0, na1;
    if (tt < NKT - 1) LOADD(na0, na1, (tt + 1) * KB)
#pragma unroll
    for (int k = 0; k < KB; k += 4) {
      double av = (double)A0[fragA + k];
      double bv = (double)A0[fragB + k];
      acc = __builtin_amdgcn_mfma_f64_16x16x4f64(av, bv, acc, 0, 0, 0);
    }
    if (tt == 0) {
      if (wid == 0) {               // layout probe on tile 0
        double q0 = (double)As[0][lane] * (double)As[0][lane];
        double q1 = (double)As[1][lane] * (double)As[0][lane];
        double q2 = (double)As[4][lane] * (double)As[0][lane];
#pragma unroll
        for (int off = 32; off; off >>= 1) {
          q0 += __shfl_down(q0, off);
          q1 += __shfl_down(q1, off);
          q2 += __shfl_down(q2, off);
        }
        if (lane == 0) { prsh[0] = q0; prsh[1] = q1; prsh[2] = q2; }
      }
      acc0 = acc;
    }
    ca0 = na0; ca1 = na1;
  }
#undef LOADD

  if (tid == 0) {
    double tol = 1e-9 * (1.0 + fabs(prsh[0]));
    int ok0  = fabs(prsh[0] - acc0[0]) <= tol;
    int okP1 = ok0 && (fabs(prsh[1] - acc0[1]) <= tol);
    int okP2 = ok0 && (fabs(prsh[2] - acc0[1]) <= tol);
    okf = okP1 ? 1 : (okP2 ? 2 : 0);
  }
  __syncthreads();
  int mode = okf;

  double (*Dt)[33] = (double(*)[33])A0;

  if (mode) {
#pragma unroll
    for (int i = 0; i < 4; ++i) {
      int lr = (mode == 1) ? (aq * 4 + i) : (aq + 4 * i);
      Dt[wi * 16 + lr][wj * 16 + (lane & 15)] = acc[i];
    }
  } else {
    // fallback: scalar f64 recompute
    double s00 = 0, s01 = 0, s10 = 0, s11 = 0;
    int ty2 = tid >> 4, tx2 = tid & 15;
    for (int kc = 0; kc < 768; kc += KB) {
      int f0 = kc + sfo;
      int c_ = f0 >> 8, h_ = (f0 >> 4) & 15, w_ = f0 & 15;
      const float* p_ = xb + c_ * IMG2 + h_ * IMG + w_;
      float4 la0 = *(const float4*)(p_ + rN), la1 = *(const float4*)(p_ + rN + 4);
      __syncthreads();
      *(float4*)&As[srow][sfo]     = la0;
      *(float4*)&As[srow][sfo + 4] = la1;
      __syncthreads();
      for (int j = 0; j < KB; ++j) {
        double a0 = (double)As[ty2][j], a1 = (double)As[ty2 + 16][j];
        double b0 = (double)As[tx2][j], b1 = (double)As[tx2 + 16][j];
        s00 += a0 * b0; s01 += a0 * b1; s10 += a1 * b0; s11 += a1 * b1;
      }
    }
    __syncthreads();
    Dt[ty2][tx2] = s00;       Dt[ty2][tx2 + 16] = s01;
    Dt[ty2 + 16][tx2] = s10;  Dt[ty2 + 16][tx2 + 16] = s11;
  }
  __syncthreads();

  // sq from Gram diagonal
  if (tid < 32) {
    double v = Dt[tid][tid];
    sqN[tid] = v;
    int n = n0b + tid;
    if (n < NTOK) sq[b * NTOK + n] = v;
  }
  __syncthreads();

  // Phase B: dist, per-batch max, coalesced write (no mirror)
  const double SQ768 = sqrt(768.0);
  int lr2 = tid >> 3, lc0 = (tid & 7) * 4;
  double dv[4];
  double lmax = 0.0;
#pragma unroll
  for (int j = 0; j < 4; ++j) {
    double d2 = sqN[lr2] + sqN[lc0 + j] - 2.0 * Dt[lr2][lc0 + j];
    double d = sqrt(d2 > 0.0 ? d2 : 0.0) / SQ768;
    dv[j] = d;
    lmax = lmax > d ? lmax : d;
  }
  red2[tid] = lmax;
  __syncthreads();
  for (int st = 128; st; st >>= 1) {
    if (tid < st) { double o = red2[tid + st]; if (o > red2[tid]) red2[tid] = o; }
    __syncthreads();
  }
  if (tid == 0) atomicMax(&dmax[b], (unsigned long long)__double_as_longlong(red2[0]));

  double* Db = dist + (size_t)b * NTOK * NTOK;
  int n = n0b + lr2, m0 = n0b + lc0;
  if (n < NTOK && m0 < NTOK) {
    if (m0 + 3 < NTOK) {
      f64x4 v = {dv[0], dv[1], dv[2], dv[3]};
      *(f64x4*)(Db + (size_t)n * NTOK + m0) = v;
    } else {
#pragma unroll
      for (int j = 0; j < 4; ++j)
        if (m0 + j < NTOK) Db[(size_t)n * NTOK + m0 + j] = dv[j];
    }
  }
}

// ---------------- K1b: off-diagonal tiles (ti<tj), R12-proven form, mirror --------
// grid: 8 xcd * 32 batch-groups * 21 offdiag-tiles = 5376 blocks of 256
__global__ void __launch_bounds__(256) k_offdiag(const float* __restrict__ x,
    const double* __restrict__ sq, double* __restrict__ dist,
    unsigned long long* __restrict__ dmax) {
  int bid = blockIdx.x;
  int xcd = bid & 7;
  int s = bid >> 3;
  int b = xcd + 8 * (s / 21);
  int t = s % 21;
  int ti = 0, rem = t, rl = 6;
  while (rem >= rl) { rem -= rl; rl--; ti++; }
  int tj = ti + 1 + rem;            // ti < tj
  int n0b = ti * 32, m0b = tj * 32;
  int tid = threadIdx.x;

  __shared__ __align__(16) float As[32][LDP];
  __shared__ __align__(16) float Bs[32][LDP];
  __shared__ int rbN[32], rbM[32];
  __shared__ double prsh[3];
  __shared__ int okf;

  if (tid < 32) {
    int n = n0b + tid; n = n < NTOK ? n : NTOK - 1;
    rbN[tid] = (n / 14) * 16 * IMG + (n % 14) * 16;
  } else if (tid < 64) {
    int m = m0b + (tid - 32); m = m < NTOK ? m : NTOK - 1;
    rbM[tid - 32] = (m / 14) * 16 * IMG + (m % 14) * 16;
  }
  __syncthreads();

  const float* xb = x + (size_t)b * 3 * IMG2;
  int srow = tid >> 3;
  int sfo  = (tid & 7) * 8;
  int rN = rbN[srow], rM = rbM[srow];
  int lane = tid & 63;
  int wid  = tid >> 6;
  int wi = wid >> 1, wj = wid & 1;
  int aq = lane >> 4;
  const float* Ap = &As[0][0];
  const float* Bp = &Bs[0][0];
  int fragA = (wi * 16 + (lane & 15)) * LDP + aq;
  int fragB = (wj * 16 + (lane & 15)) * LDP + aq;

#define LOADT(d0,d1,d2,d3,kc) { int f0 = (kc) + sfo;                         \
    int c_ = f0 >> 8, h_ = (f0 >> 4) & 15, w_ = f0 & 15;                     \
    const float* p_ = xb + c_ * IMG2 + h_ * IMG + w_;                        \
    d0 = *(const float4*)(p_ + rN); d1 = *(const float4*)(p_ + rN + 4);      \
    d2 = *(const float4*)(p_ + rM); d3 = *(const float4*)(p_ + rM + 4); }

  f64x4 acc = {0.0, 0.0, 0.0, 0.0};
  f64x4 acc0 = {0.0, 0.0, 0.0, 0.0};
  float4 ca0, ca1, cb0, cb1;
  LOADT(ca0, ca1, cb0, cb1, 0)

#pragma unroll
  for (int tt = 0; tt < NKT; ++tt) {
    __syncthreads();
    *(float4*)&As[srow][sfo]     = ca0;
    *(float4*)&As[srow][sfo + 4] = ca1;
    *(float4*)&Bs[srow][sfo]     = cb0;
    *(float4*)&Bs[srow][sfo + 4] = cb1;
    __syncthreads();
    float4 na0, na1, nb0, nb1;
    if (tt < NKT - 1) LOADT(na0, na1, nb0, nb1, (tt + 1) * KB)
#pragma unroll
    for (int k = 0; k < KB; k += 4) {
      double av = (double)Ap[fragA + k];
      double bv = (double)Bp[fragB + k];
      acc = __builtin_amdgcn_mfma_f64_16x16x4f64(av, bv, acc, 0, 0, 0);
    }
    if (tt == 0) {
      if (wid == 0) {
        double q0 = (double)As[0][lane] * (double)Bs[0][lane];
        double q1 = (double)As[1][lane] * (double)Bs[0][lane];
        double q2 = (double)As[4][lane] * (double)Bs[0][lane];
#pragma unroll
        for (int off = 32; off; off >>= 1) {
          q0 += __shfl_down(q0, off);
          q1 += __shfl_down(q1, off);
          q2 += __shfl_down(q2, off);
        }
        if (lane == 0) { prsh[0] = q0; prsh[1] = q1; prsh[2] = q2; }
      }
      acc0 = acc;
    }
    ca0 = na0; ca1 = na1; cb0 = nb0; cb1 = nb1;
  }
#undef LOADT

  if (tid == 0) {
    double tol = 1e-9 * (1.0 + fabs(prsh[0]));
    int ok0  = fabs(prsh[0] - acc0[0]) <= tol;
    int okP1 = ok0 && (fabs(prsh[1] - acc0[1]) <= tol);
    int okP2 = ok0 && (fabs(prsh[2] - acc0[1]) <= tol);
    okf = okP1 ? 1 : (okP2 ? 2 : 0);
  }
  __syncthreads();
  int mode = okf;

  double (*Dt)[33] = (double(*)[33])Ap;

  if (mode) {
#pragma unroll
    for (int i = 0; i < 4; ++i) {
      int lr = (mode == 1) ? (aq * 4 + i) : (aq + 4 * i);
      Dt[wi * 16 + lr][wj * 16 + (lane & 15)] = acc[i];
    }
  } else {
    double s00 = 0, s01 = 0, s10 = 0, s11 = 0;
    int ty2 = tid >> 4, tx2 = tid & 15;
    for (int kc = 0; kc < 768; kc += KB) {
      int f0 = kc + sfo;
      int c_ = f0 >> 8, h_ = (f0 >> 4) & 15, w_ = f0 & 15;
      const float* p_ = xb + c_ * IMG2 + h_ * IMG + w_;
      float4 la0 = *(const float4*)(p_ + rN), la1 = *(const float4*)(p_ + rN + 4);
      float4 lb0 = *(const float4*)(p_ + rM), lb1 = *(const float4*)(p_ + rM + 4);
      __syncthreads();
      *(float4*)&As[srow][sfo]     = la0;
      *(float4*)&As[srow][sfo + 4] = la1;
      *(float4*)&Bs[srow][sfo]     = lb0;
      *(float4*)&Bs[srow][sfo + 4] = lb1;
      __syncthreads();
      for (int j = 0; j < KB; ++j) {
        double a0 = (double)As[ty2][j], a1 = (double)As[ty2 + 16][j];
        double b0 = (double)Bs[tx2][j], b1 = (double)Bs[tx2 + 16][j];
        s00 += a0 * b0; s01 += a0 * b1; s10 += a1 * b0; s11 += a1 * b1;
      }
    }
    __syncthreads();
    Dt[ty2][tx2] = s00;       Dt[ty2][tx2 + 16] = s01;
    Dt[ty2 + 16][tx2] = s10;  Dt[ty2 + 16][tx2 + 16] = s11;
  }
  __syncthreads();

  // Phase B: dist, per-batch max, coalesced writes + mirror
  const double* sqb = sq + b * NTOK;
  const double SQ768 = sqrt(768.0);
  int lr2 = tid >> 3, lc0 = (tid & 7) * 4;
  double dv[4];
  double lmax = 0.0;
#pragma unroll
  for (int j = 0; j < 4; ++j) {
    int n = n0b + lr2, m = m0b + lc0 + j;
    int nn = n < NTOK ? n : NTOK - 1, mm = m < NTOK ? m : NTOK - 1;
    double d2 = sqb[nn] + sqb[mm] - 2.0 * Dt[lr2][lc0 + j];
    double d = sqrt(d2 > 0.0 ? d2 : 0.0) / SQ768;
    dv[j] = d;
    lmax = lmax > d ? lmax : d;
  }
#pragma unroll
  for (int j = 0; j < 4; ++j) Dt[lr2][lc0 + j] = dv[j];  // keep for mirror reads
  double* red = (double*)Bp;
  red[tid] = lmax;
  __syncthreads();
  for (int st = 128; st; st >>= 1) {
    if (tid < st) { double o = red[tid + st]; if (o > red[tid]) red[tid] = o; }
    __syncthreads();
  }
  if (tid == 0) atomicMax(&dmax[b], (unsigned long long)__double_as_longlong(red[0]));

  double* Db = dist + (size_t)b * NTOK * NTOK;
  {
    int n = n0b + lr2, m0 = m0b + lc0;
    if (n < NTOK && m0 < NTOK) {
      if (m0 + 3 < NTOK) {
        f64x4 v = {dv[0], dv[1], dv[2], dv[3]};
        *(f64x4*)(Db + (size_t)n * NTOK + m0) = v;
      } else {
#pragma unroll
        for (int j = 0; j < 4; ++j)
          if (m0 + j < NTOK) Db[(size_t)n * NTOK + m0 + j] = dv[j];
      }
    }
  }
  {
    int m = m0b + lr2, n0 = n0b + lc0;
    if (m < NTOK && n0 < NTOK) {
      if (n0 + 3 < NTOK) {
        f64x4 v = {Dt[lc0][lr2], Dt[lc0 + 1][lr2], Dt[lc0 + 2][lr2], Dt[lc0 + 3][lr2]};
        *(f64x4*)(Db + (size_t)m * NTOK + n0) = v;
      } else {
#pragma unroll
        for (int j = 0; j < 4; ++j)
          if (n0 + j < NTOK) Db[(size_t)m * NTOK + n0 + j] = Dt[lc0 + j][lr2];
      }
    }
  }
}

// 5-NN insert (ascending 5-list in registers)
#define INS5(n0_,n1_,n2_,n3_,n4_,v_) {                                        \
  if ((v_) < n4_) { n4_ = (v_);                                               \
    if (n4_ < n3_) { double w_ = n3_; n3_ = n4_; n4_ = w_;                    \
      if (n3_ < n2_) { w_ = n2_; n2_ = n3_; n3_ = w_;                         \
        if (n2_ < n1_) { w_ = n1_; n1_ = n2_; n2_ = w_;                       \
          if (n1_ < n0_) { w_ = n0_; n0_ = n1_; n1_ = w_; } } } } } }

// merge two ascending 5-lists -> 5 smallest (ascending) into a[]
__device__ __forceinline__ void merge5(double a[5], const double b[5]) {
  double o[5];
  double ax = a[0], a1 = a[1], a2 = a[2], a3 = a[3], a4 = a[4];
  double bx = b[0], b1 = b[1], b2 = b[2], b3 = b[3], b4 = b[4];
#pragma unroll
  for (int p = 0; p < 5; ++p) {
    if (ax <= bx) { o[p] = ax; ax = a1; a1 = a2; a2 = a3; a3 = a4; a4 = 1e300; }
    else          { o[p] = bx; bx = b1; b1 = b2; b2 = b3; b3 = b4; b4 = 1e300; }
  }
#pragma unroll
  for (int p = 0; p < 5; ++p) a[p] = o[p];
}

// ---------------- K2: fused clustering, 1024 threads, 4-way m-scan split ----------
__global__ void __launch_bounds__(1024) k_cluster4(const double* __restrict__ dist,
    const unsigned long long* __restrict__ dmax, int* __restrict__ out,
    uint32_t kd0, uint32_t kd1, uint32_t kn0, uint32_t kn1, int B) {
  int b = blockIdx.x;
  int tid = threadIdx.x;
  int lane = tid & 63, wid = tid >> 6;
  int t = tid & 255, q = tid >> 8;
  bool act = t < NTOK;
  int m0 = q * 49;
  const double* Db = dist + (size_t)b * NTOK * NTOK;
  __shared__ double nbsh[2][NTOK][5];
  __shared__ double dens[NTOK];
  __shared__ double score[NTOK];
  __shared__ int center[KCL];
  __shared__ short center_of[NTOK];
  __shared__ unsigned long long bkey[KCL];
  double dmaxv = __longlong_as_double((long long)dmax[b]);

  // P1: partial 5-NN over quarter of the row (coalesced: Db[m][t]==dist[t][m])
  double nb[5] = {1e300, 1e300, 1e300, 1e300, 1e300};
  if (act) {
    const double* base = Db + t;
    for (int i = 0; i < 49; ++i) {
      double v = base[(size_t)(m0 + i) * NTOK];
      INS5(nb[0], nb[1], nb[2], nb[3], nb[4], v)
    }
    if (q == 1) {
#pragma unroll
      for (int p = 0; p < 5; ++p) nbsh[0][t][p] = nb[p];
    } else if (q == 3) {
#pragma unroll
      for (int p = 0; p < 5; ++p) nbsh[1][t][p] = nb[p];
    }
  }
  __syncthreads();
  if (act && q == 2) {             // merge q2+q3 -> nbsh[1]
    double ob[5];
#pragma unroll
    for (int p = 0; p < 5; ++p) ob[p] = nbsh[1][t][p];
    merge5(nb, ob);
#pragma unroll
    for (int p = 0; p < 5; ++p) nbsh[1][t][p] = nb[p];
  }
  __syncthreads();
  if (tid < NTOK) {                // q0: merge own+q1, then +(q2+q3)
    double ob[5];
#pragma unroll
    for (int p = 0; p < 5; ++p) ob[p] = nbsh[0][t][p];
    merge5(nb, ob);
#pragma unroll
    for (int p = 0; p < 5; ++p) ob[p] = nbsh[1][t][p];
    merge5(nb, ob);
    double acc = 0.0;
#pragma unroll
    for (int p = 0; p < 5; ++p) acc += nb[p] * nb[p];   // ascending sum
    double d = exp(-(acc / 5.0));
    double u = (double)jax_uniform(kd0, kd1, (uint32_t)(b * NTOK + t));
    dens[t] = d + u * 1e-6;
  }
  __syncthreads();

  // P2: dmin over strictly-higher-density tokens (filler = dist_max), 4-way split
  double vloc = dmaxv;
  if (act) {
    double dn = dens[t];
    const double* base = Db + t;
    for (int i = 0; i < 49; ++i) {
      double r = base[(size_t)(m0 + i) * NTOK];
      if (dens[m0 + i] > dn && r < vloc) vloc = r;
    }
  }
  __syncthreads();
  double* pm = &nbsh[0][0][0];
  if (act && q > 0) pm[(q - 1) * NTOK + t] = vloc;
  __syncthreads();
  if (tid < NTOK) {
    double v = vloc;
    double p1v = pm[t], p2v = pm[NTOK + t], p3v = pm[2 * NTOK + t];
    v = p1v < v ? p1v : v;
    v = p2v < v ? p2v : v;
    v = p3v < v ? p3v : v;
    score[t] = v * dens[t];
  }
  __syncthreads();

  // P3: iterative top-49 (ties -> lower index) on wave 0, scores in registers
  if (wid == 0) {
    double s0 = (lane < NTOK) ? score[lane] : -1e300;
    double s1 = score[lane + 64];
    double s2 = score[lane + 128];
    double s3 = (lane + 192 < NTOK) ? score[lane + 192] : -1e300;
    for (int k = 0; k < KCL; ++k) {
      double mv = s0; int mi = lane;
      if (s1 > mv) { mv = s1; mi = lane + 64; }
      if (s2 > mv) { mv = s2; mi = lane + 128; }
      if (s3 > mv) { mv = s3; mi = lane + 192; }
#pragma unroll
      for (int off = 32; off; off >>= 1) {
        double ov = __shfl_down(mv, off); int oi = __shfl_down(mi, off);
        if (ov > mv || (ov == mv && oi < mi)) { mv = ov; mi = oi; }
      }
      mi = __shfl(mi, 0);
      if (lane == 0) center[k] = mi;
      if (mi == lane) s0 = -1e300;
      else if (mi == lane + 64) s1 = -1e300;
      else if (mi == lane + 128) s2 = -1e300;
      else if (mi == lane + 192) s3 = -1e300;
    }
  }
  __syncthreads();

  // P4: assign to nearest center (ties -> lower k), centers self-assign
  if (tid < NTOK) center_of[tid] = -1;
  __syncthreads();
  if (tid < KCL) { center_of[center[tid]] = (short)tid; bkey[tid] = 0ULL; }
  __syncthreads();
  int mycl = 0;
  if (tid < NTOK) {
    double best = 1e300; int bk = 0;
    for (int k = 0; k < KCL; ++k) {
      double d = Db[(size_t)center[k] * NTOK + tid];
      if (d < best) { best = d; bk = k; }
    }
    short co = center_of[tid];
    if (co >= 0) bk = co;
    mycl = bk;
  }
  __syncthreads();

  // P5: representative = per-cluster max of f32 key (k+u), ties -> larger token index
  if (tid < NTOK) {
    float u = jax_uniform(kn0, kn1, (uint32_t)(b * NTOK + tid));
    float keyf = (float)mycl + u;
    unsigned long long key =
        ((unsigned long long)__float_as_uint(keyf) << 8) | (unsigned)tid;
    atomicMax(&bkey[mycl], key);
  }
  __syncthreads();
  if (tid < KCL) out[b * KCL + tid] = (int)(bkey[tid] & 0xFFu);
}

// ---------------- launch ----------------
extern "C" void kernel_launch(void* const* d_in, const int* in_sizes, int n_in,
                              void* d_out, int out_size, void* d_ws, size_t ws_size,
                              hipStream_t stream) {
  const float* x = (const float*)d_in[0];
  int B = in_sizes[0] / (3 * IMG2);           // 256
  double* dist = (double*)d_ws;
  size_t distBytes = (size_t)B * NTOK * NTOK * sizeof(double);
  double* sq = (double*)((char*)d_ws + distBytes);
  unsigned long long* dmax =
      (unsigned long long*)((char*)sq + (size_t)B * NTOK * sizeof(double));
  int* out = (int*)d_out;

  uint32_t kd0, kd1, kn0, kn1;
  tf2x32(0u, 1u, 0u, 0u, &kd0, &kd1);
  tf2x32(0u, 1u, 0u, 1u, &kn0, &kn1);

  hipMemsetAsync(dmax, 0, B * sizeof(unsigned long long), stream);
  k_diag<<<dim3(8 * 32 * 7), dim3(256), 0, stream>>>(x, sq, dist, dmax);
  k_offdiag<<<dim3(8 * 32 * 21), dim3(256), 0, stream>>>(x, sq, dist, dmax);
  k_cluster4<<<dim3(B), dim3(1024), 0, stream>>>(dist, dmax, out, kd0, kd1, kn0, kn1, B);
}